// Round 19
// baseline (141.726 us; speedup 1.0000x reference)
//
#include <hip/hip_runtime.h>
#include <math.h>

#define BB 4
#define NN 512
#define DD 256
#define HH 8
#define BND (BB*NN*DD)

typedef _Float16 h2 __attribute__((ext_vector_type(2)));
typedef _Float16 f16x4 __attribute__((ext_vector_type(4)));
typedef _Float16 f16x8 __attribute__((ext_vector_type(8)));
typedef float    f32x4 __attribute__((ext_vector_type(4)));

static __device__ __forceinline__ h2 u2h(unsigned u) { return __builtin_bit_cast(h2, u); }
// RNE pack (features/logits/GEMM inputs)
static __device__ __forceinline__ h2 pk2(float a, float b) {
    h2 r; r[0] = (_Float16)a; r[1] = (_Float16)b; return r;
}
static __device__ __forceinline__ unsigned pk2u(float a, float b) {
    return __builtin_bit_cast(unsigned, pk2(a, b));
}
// RTZ pack (hidden only — R9-proven)
static __device__ __forceinline__ h2 pkz(float a, float b) {
    return __builtin_bit_cast(h2, __builtin_amdgcn_cvt_pkrtz(a, b));
}
static __device__ __forceinline__ float dot2(h2 a, h2 b, float c) {
    return __builtin_amdgcn_fdot2(a, b, c, false);
}

// ---------------- pack: Wt[1024][256] f16, Wt[n][k] = W*[k][n] ----------------
__global__ __launch_bounds__(256) void pack_wt(
    const float* __restrict__ Wq, const float* __restrict__ Wk,
    const float* __restrict__ Wv, const float* __restrict__ Wo,
    _Float16* __restrict__ wt)
{
    __shared__ float T[64][65];
    const int t  = threadIdx.x;
    const int nb = blockIdx.x >> 2;   // 16 n-blocks of 64
    const int kb = blockIdx.x & 3;    // 4 k-blocks of 64
    const int tn = t & 63;
    const int tr = t >> 6;
    const int nbase = nb * 64;
    const float* W = (nbase < 256) ? Wq : (nbase < 512) ? Wk : (nbase < 768) ? Wv : Wo;
    const int noff = nbase & 255;
    #pragma unroll
    for (int r = 0; r < 16; ++r) {
        const int kl = tr*16 + r;
        T[kl][tn] = W[(size_t)(kb*64 + kl)*DD + noff + tn];
    }
    __syncthreads();
    #pragma unroll
    for (int r = 0; r < 16; ++r) {
        const int nl = tr*16 + r;
        wt[(size_t)(nbase + nl)*DD + kb*64 + tn] = (_Float16)T[tn][nl];
    }
}

// ---------------- qkv via MFMA (R13-exact) ----------------
__global__ __launch_bounds__(64) void gemm_qkv(
    const float* __restrict__ hg, const int* __restrict__ mask,
    const _Float16* __restrict__ wt,
    _Float16* __restrict__ q16, _Float16* __restrict__ k16, _Float16* __restrict__ v16h)
{
    const int l  = threadIdx.x;
    const int lo = l & 15, g = l >> 4;
    const int bid = blockIdx.x;         // 128 row-tiles x 24 col-tiles
    const int rt = bid / 24, ct = bid % 24;
    const int R0 = rt*16, C0 = ct*32;
    const int row = R0 + lo;
    const float msc = (mask[row] != 0) ? 1.f : 0.f;

    const float*    xrow = hg + (size_t)row*DD;
    const _Float16* w0   = wt + (size_t)(C0 + lo)*DD;
    const _Float16* w1   = wt + (size_t)(C0 + 16 + lo)*DD;
    f32x4 ac0 = {0.f,0.f,0.f,0.f}, ac1 = {0.f,0.f,0.f,0.f};
    #pragma unroll
    for (int kk = 0; kk < 16; ++kk) {
        const float4 xv = *(const float4*)(xrow + kk*16 + g*4);
        f16x4 a;
        a[0] = (_Float16)(xv.x * msc);
        a[1] = (_Float16)(xv.y * msc);
        a[2] = (_Float16)(xv.z * msc);
        a[3] = (_Float16)(xv.w * msc);
        const f16x4 b0 = *(const f16x4*)(w0 + kk*16 + g*4);
        const f16x4 b1 = *(const f16x4*)(w1 + kk*16 + g*4);
        ac0 = __builtin_amdgcn_mfma_f32_16x16x16f16(a, b0, ac0, 0, 0, 0);
        ac1 = __builtin_amdgcn_mfma_f32_16x16x16f16(a, b1, ac1, 0, 0, 0);
    }
    const float qscale = 0.17677669529663687f; // 1/sqrt(32)
    #pragma unroll
    for (int ci = 0; ci < 2; ++ci) {
        const f32x4 ac = ci ? ac1 : ac0;
        const int col = C0 + ci*16 + lo;
        const int seg = col >> 8;          // 0=q 1=k 2=v
        const int cc  = col & 255;
        #pragma unroll
        for (int r = 0; r < 4; ++r) {
            const int ro = R0 + g*4 + r;
            const float val = ac[r];
            if (seg == 0)      q16[(size_t)ro*DD + cc] = (_Float16)val;
            else if (seg == 1) k16[(size_t)ro*DD + cc] = (_Float16)(val * qscale);
            else               v16h[((size_t)(ro >> 1)*DD + cc)*2 + (ro & 1)] = (_Float16)val;
        }
    }
}

// ---------------- kernel A: bias-MLP + QK, i-tile=16, split-pack ----------------
// block = (b, i-tile of 16, j-eighth of 64). 1024 blocks, 4 waves; wave w owns
// j-tile je*64 + w*16. TWO passes of 8 i reuse a [8][132] buffer -> LDS 17.2KB
// -> launch_bounds(256,6) = 6 blocks/CU (was 3 at 34.3KB). VGPR cap 85 vs
// measured need 60 (R17) -> spill-free. QK MFMAs recomputed per pass (+76cyc).
__global__ __launch_bounds__(256, 6) void bias_qk(
    const _Float16* __restrict__ q16, const _Float16* __restrict__ k16,
    const float* __restrict__ p, const int* __restrict__ side, const int* __restrict__ mask,
    const float* __restrict__ W1, const float* __restrict__ b1,
    const float* __restrict__ W2, const float* __restrict__ b2,
    unsigned* __restrict__ logitsH)
{
    __shared__ float bsm[4][8*132];    // per-wave logits [i_local][h*16 + j], stride 132
    __shared__ float pis[16][2];
    __shared__ int   sis[16];

    const int t  = threadIdx.x;
    const int w  = t >> 6;
    const int l  = t & 63;
    const int lo = l & 15;
    const int g  = l >> 4;

    const int bid = blockIdx.x;
    const int b   = bid >> 8;
    const int it  = (bid >> 3) & 31;
    const int je  = bid & 7;
    const int i0  = it * 16;
    const int jb  = je * 64 + w * 16;   // this wave's j-tile
    const int j   = jb + lo;            // this lane's key column

    if (t < 16) {
        const float2 pp = ((const float2*)p)[b*NN + i0 + t];
        pis[t][0] = pp.x; pis[t][1] = pp.y;
        sis[t] = side[b*NN + i0 + t];
    }
    __syncthreads();

    const f16x4 z4 = {(_Float16)0.f,(_Float16)0.f,(_Float16)0.f,(_Float16)0.f};
    const f32x4 zf = {0.f,0.f,0.f,0.f};
    const h2 zz = {(_Float16)0.f, (_Float16)0.f};

    // A1: W1ext^T[hid][k] with relabeled rows (k: 0..3 feats, 4 bias-one, 5..15 zero)
    f16x4 a1[16];
    #pragma unroll
    for (int m = 0; m < 16; ++m) {
        const int hid = ((m >> 1) << 5) + ((lo >> 2) << 3) + ((m & 1) << 2) + (lo & 3);
        f16x4 v = z4;
        const float w0 = W1[hid], w1 = W1[256+hid], w2 = W1[512+hid], w3 = W1[768+hid];
        const float bb1 = b1[hid];
        if (g == 0) { v[0]=(_Float16)w0; v[1]=(_Float16)w1; v[2]=(_Float16)w2; v[3]=(_Float16)w3; }
        else if (g == 1) { v[0]=(_Float16)bb1; }
        a1[m] = v;
    }
    // A2 (K=32): W2^T[h][hid], lane (lo,g) holds k = g*8+e -> hid = s*32 + g*8 + e
    f16x8 a2[8];
    #pragma unroll
    for (int s = 0; s < 8; ++s) {
        const int base = s*32 + g*8;
        const int hs   = lo & 7;
        f16x8 v;
        #pragma unroll
        for (int e = 0; e < 8; ++e) v[e] = (lo < 8) ? (_Float16)W2[(base+e)*HH + hs] : (_Float16)0.f;
        a2[s] = v;
    }
    // b2 addend for epilogue rows h = g*4+r (only l<32 stores)
    float b2v[4];
    #pragma unroll
    for (int r = 0; r < 4; ++r) b2v[r] = (g < 2) ? b2[(g*4 + r) & 7] : 0.f;

    const float2 pj = ((const float2*)p)[b*NN + j];
    const int   sj  = side[b*NN + j];
    const float km  = mask[b*NN + j] ? 0.f : -3.0e4f;

    const _Float16* qbase = q16 + (size_t)(b*NN + i0 + lo)*DD;
    const _Float16* kbase = k16 + (size_t)(b*NN + j)*DD;

    float* bw = &bsm[w][0];

    #pragma unroll
    for (int pass = 0; pass < 2; ++pass) {
        const int ib = pass * 8;

        // ---- MLP: 8 pair-groups (group = query row i, cols = 16 j) ----
        #pragma unroll 2
        for (int il = 0; il < 8; ++il) {
            const int i = ib + il;
            const float pix = pis[i][0], piy = pis[i][1];
            const int   sii = sis[i];
            const float dx = pix - pj.x;
            const float dy = piy - pj.y;
            const float di = fmaxf(sqrtf(dx*dx + dy*dy), 1e-6f);
            const float tm = (sii == sj) ? 1.f : 0.f;
            const h2 fA = pk2(dx, dy);   // RNE on features
            const h2 fB = pk2(di, tm);
            f16x4 bf = z4;
            if (g == 0) { bf[0]=fA[0]; bf[1]=fA[1]; bf[2]=fB[0]; bf[3]=fB[1]; }
            else if (g == 1) { bf[0] = (_Float16)1.f; }

            f32x4 e0 = zf, e1 = zf;
            #pragma unroll
            for (int s = 0; s < 8; ++s) {
                const f32x4 c1a = __builtin_amdgcn_mfma_f32_16x16x16f16(a1[2*s],   bf, zf, 0, 0, 0);
                const f32x4 c1b = __builtin_amdgcn_mfma_f32_16x16x16f16(a1[2*s+1], bf, zf, 0, 0, 0);
                const h2 ra01 = __builtin_elementwise_max(pkz(c1a[0], c1a[1]), zz);
                const h2 ra23 = __builtin_elementwise_max(pkz(c1a[2], c1a[3]), zz);
                const h2 rb01 = __builtin_elementwise_max(pkz(c1b[0], c1b[1]), zz);
                const h2 rb23 = __builtin_elementwise_max(pkz(c1b[2], c1b[3]), zz);
                f16x8 hb;
                hb[0]=ra01[0]; hb[1]=ra01[1]; hb[2]=ra23[0]; hb[3]=ra23[1];
                hb[4]=rb01[0]; hb[5]=rb01[1]; hb[6]=rb23[0]; hb[7]=rb23[1];
                if (s & 1) e1 = __builtin_amdgcn_mfma_f32_16x16x32_f16(a2[s], hb, e1, 0, 0, 0);
                else       e0 = __builtin_amdgcn_mfma_f32_16x16x32_f16(a2[s], hb, e0, 0, 0, 0);
            }
            if (l < 32) {
                #pragma unroll
                for (int r = 0; r < 4; ++r)
                    bw[il*132 + (g*4 + r)*16 + lo] = e0[r] + e1[r] + b2v[r] + km;
            }
        }

        asm volatile("s_waitcnt lgkmcnt(0)" ::: "memory");
        __builtin_amdgcn_sched_barrier(0);

        // ---- QK: one K=32 MFMA per head; merge rows belonging to this pass ----
        // C rows i = g*4+r; pass p owns i in [8p, 8p+8) -> lanes with (g>>1)==p.
        {
            #pragma unroll
            for (int h = 0; h < 8; ++h) {
                const f16x8 q8 = *(const f16x8*)(qbase + h*32 + g*8);
                const f16x8 k8 = *(const f16x8*)(kbase + h*32 + g*8);
                const f32x4 qk = __builtin_amdgcn_mfma_f32_16x16x32_f16(q8, k8, zf, 0, 0, 0);
                if ((g >> 1) == pass) {
                    const int il = (g & 1)*4;
                    #pragma unroll
                    for (int r = 0; r < 4; ++r)
                        bw[(il + r)*132 + h*16 + lo] += qk[r];
                }
            }
        }

        asm volatile("s_waitcnt lgkmcnt(0)" ::: "memory");
        __builtin_amdgcn_sched_barrier(0);

        // ---- pack f16 j-pairs and store: iter u = local row; lane -> (h, jp) ----
        {
            const int hh = (l >> 3) & 7;
            const int jp = l & 7;
            #pragma unroll
            for (int u = 0; u < 8; ++u) {
                const float2 v2 = *(const float2*)&bw[u*132 + hh*16 + 2*jp];
                logitsH[((size_t)((b*NN + i0 + ib + u)*HH + hh))*(NN/2) + (jb >> 1) + jp] =
                    pk2u(v2.x, v2.y);
            }
        }
        asm volatile("s_waitcnt lgkmcnt(0)" ::: "memory");
        __builtin_amdgcn_sched_barrier(0);
    }
}

// ---------------- kernel B: softmax + PV (R13-exact) ----------------
__global__ __launch_bounds__(256, 4) void attn_sm(
    const unsigned* __restrict__ logitsH, const unsigned* __restrict__ v16p,
    float* __restrict__ ao)
{
    __shared__ unsigned Lgh[16][260];
    __shared__ float red[16][16];
    __shared__ float mx[16];
    __shared__ float rs[16];

    const int t  = threadIdx.x;
    const int b  = blockIdx.x / (NN/2);
    const int i0 = (blockIdx.x % (NN/2)) * 2;

    #pragma unroll
    for (int ii = 0; ii < 2; ++ii)
        #pragma unroll
        for (int hh = 0; hh < HH; ++hh)
            Lgh[ii*8 + hh][t] = logitsH[((size_t)((b*NN + i0 + ii)*HH + hh))*(NN/2) + t];
    __syncthreads();

    const int combo = t >> 4;
    const int sub   = t & 15;
    {
        h2 pm = u2h(0xFC00FC00u);
        for (int jp = sub; jp < NN/2; jp += 16)
            pm = __builtin_elementwise_max(pm, u2h(Lgh[combo][jp]));
        red[combo][sub] = fmaxf((float)pm[0], (float)pm[1]);
    }
    __syncthreads();
    if (t < 16) {
        float mm = red[t][0];
        #pragma unroll
        for (int s = 1; s < 16; ++s) mm = fmaxf(mm, red[t][s]);
        mx[t] = mm;
    }
    __syncthreads();
    {
        const float M = mx[combo];
        float s = 0.f;
        for (int jp = sub; jp < NN/2; jp += 16) {
            const h2 lg = u2h(Lgh[combo][jp]);
            const float e0 = __expf((float)lg[0] - M);
            const float e1 = __expf((float)lg[1] - M);
            s += e0 + e1;
            Lgh[combo][jp] = pk2u(e0, e1);
        }
        red[combo][sub] = s;
    }
    __syncthreads();
    if (t < 16) {
        float s = 0.f;
        #pragma unroll
        for (int ss = 0; ss < 16; ++ss) s += red[t][ss];
        rs[t] = 1.f / s;
    }
    __syncthreads();

    {
        const int c = t;
        const int hh = c >> 5;
        const unsigned* vb = v16p + (size_t)b*(NN/2)*DD + c;
        float o[2] = {0.f, 0.f};
        for (int jp = 0; jp < NN/2; ++jp) {
            const h2 vp = u2h(vb[(size_t)jp*DD]);
            #pragma unroll
            for (int ii = 0; ii < 2; ++ii)
                o[ii] = dot2(u2h(Lgh[ii*8 + hh][jp]), vp, o[ii]);
        }
        #pragma unroll
        for (int ii = 0; ii < 2; ++ii)
            ao[(size_t)(b*NN + i0 + ii)*DD + c] = o[ii] * rs[ii*8 + hh];
    }
}

// ---------------- output projection via MFMA (R13-exact) ----------------
__global__ __launch_bounds__(64) void gemm_o(
    const float* __restrict__ X, const _Float16* __restrict__ wt,
    float* __restrict__ Y)
{
    const int l  = threadIdx.x;
    const int lo = l & 15, g = l >> 4;
    const int bid = blockIdx.x;         // 128 row-tiles x 8 col-tiles
    const int rt = bid >> 3, ct = bid & 7;
    const int R0 = rt*16, C0 = ct*32;
    const int row = R0 + lo;

    const float*    xrow = X + (size_t)row*DD;
    const _Float16* w0   = wt + (size_t)(C0 + lo)*DD;
    const _Float16* w1   = wt + (size_t)(C0 + 16 + lo)*DD;
    f32x4 ac0 = {0.f,0.f,0.f,0.f}, ac1 = {0.f,0.f,0.f,0.f};
    #pragma unroll
    for (int kk = 0; kk < 16; ++kk) {
        const float4 xv = *(const float4*)(xrow + kk*16 + g*4);
        f16x4 a;
        a[0] = (_Float16)xv.x;
        a[1] = (_Float16)xv.y;
        a[2] = (_Float16)xv.z;
        a[3] = (_Float16)xv.w;
        const f16x4 b0 = *(const f16x4*)(w0 + kk*16 + g*4);
        const f16x4 b1 = *(const f16x4*)(w1 + kk*16 + g*4);
        ac0 = __builtin_amdgcn_mfma_f32_16x16x16f16(a, b0, ac0, 0, 0, 0);
        ac1 = __builtin_amdgcn_mfma_f32_16x16x16f16(a, b1, ac1, 0, 0, 0);
    }
    #pragma unroll
    for (int ci = 0; ci < 2; ++ci) {
        const f32x4 ac = ci ? ac1 : ac0;
        const int col = C0 + ci*16 + lo;
        #pragma unroll
        for (int r = 0; r < 4; ++r)
            Y[(size_t)(R0 + g*4 + r)*DD + col] = ac[r];
    }
}

extern "C" void kernel_launch(void* const* d_in, const int* in_sizes, int n_in,
                              void* d_out, int out_size, void* d_ws, size_t ws_size,
                              hipStream_t stream) {
    const float* hg   = (const float*)d_in[0];
    const float* p    = (const float*)d_in[1];
    const int*   side = (const int*)d_in[2];
    const int*   mask = (const int*)d_in[3];
    const float* Wq   = (const float*)d_in[4];
    const float* Wk   = (const float*)d_in[5];
    const float* Wv   = (const float*)d_in[6];
    const float* Wo   = (const float*)d_in[7];
    const float* W1   = (const float*)d_in[8];
    const float* b1   = (const float*)d_in[9];
    const float* W2   = (const float*)d_in[10];
    const float* b2   = (const float*)d_in[11];

    float* ws = (float*)d_ws;
    float* ao = ws;                                   // BND f32
    _Float16* q16 = (_Float16*)(ws + BND);            // BND f16
    _Float16* k16 = q16 + BND;                        // BND f16
    _Float16* v16 = k16 + BND;                        // BND f16 (packed pairs)
    unsigned* logitsH = (unsigned*)(v16 + BND);       // B*N*H*(N/2) dwords
    _Float16* wt16 = (_Float16*)(logitsH + (size_t)BB*NN*HH*(NN/2));  // [1024][256]

    pack_wt<<<64, 256, 0, stream>>>(Wq, Wk, Wv, Wo, wt16);
    gemm_qkv<<<128*24, 64, 0, stream>>>(hg, mask, wt16, q16, k16, v16);
    bias_qk<<<1024, 256, 0, stream>>>(q16, k16, p, side, mask, W1, b1, W2, b2, logitsH);
    attn_sm<<<BB*(NN/2), 256, 0, stream>>>(logitsH, (const unsigned*)v16, ao);
    gemm_o<<<128*8, 64, 0, stream>>>(ao, wt16 + (size_t)768*DD, (float*)d_out);
}

// Round 20
// 91.411 us; speedup vs baseline: 1.5504x; 1.5504x over previous
//
#include <hip/hip_runtime.h>
#include <math.h>

#define BB 4
#define NN 512
#define DD 256
#define HH 8
#define BND (BB*NN*DD)

typedef _Float16 h2 __attribute__((ext_vector_type(2)));
typedef _Float16 f16x4 __attribute__((ext_vector_type(4)));
typedef float    f32x4 __attribute__((ext_vector_type(4)));

static __device__ __forceinline__ h2 u2h(unsigned u) { return __builtin_bit_cast(h2, u); }
// RNE pack (features/logits/GEMM inputs)
static __device__ __forceinline__ h2 pk2(float a, float b) {
    h2 r; r[0] = (_Float16)a; r[1] = (_Float16)b; return r;
}
static __device__ __forceinline__ unsigned pk2u(float a, float b) {
    return __builtin_bit_cast(unsigned, pk2(a, b));
}
// RTZ pack (hidden only — R9-proven)
static __device__ __forceinline__ h2 pkz(float a, float b) {
    return __builtin_bit_cast(h2, __builtin_amdgcn_cvt_pkrtz(a, b));
}
static __device__ __forceinline__ float dot2(h2 a, h2 b, float c) {
    return __builtin_amdgcn_fdot2(a, b, c, false);
}

// ---------------- pack: Wt[1024][256] f16, Wt[n][k] = W*[k][n] ----------------
__global__ __launch_bounds__(256) void pack_wt(
    const float* __restrict__ Wq, const float* __restrict__ Wk,
    const float* __restrict__ Wv, const float* __restrict__ Wo,
    _Float16* __restrict__ wt)
{
    __shared__ float T[64][65];
    const int t  = threadIdx.x;
    const int nb = blockIdx.x >> 2;   // 16 n-blocks of 64
    const int kb = blockIdx.x & 3;    // 4 k-blocks of 64
    const int tn = t & 63;
    const int tr = t >> 6;
    const int nbase = nb * 64;
    const float* W = (nbase < 256) ? Wq : (nbase < 512) ? Wk : (nbase < 768) ? Wv : Wo;
    const int noff = nbase & 255;
    #pragma unroll
    for (int r = 0; r < 16; ++r) {
        const int kl = tr*16 + r;
        T[kl][tn] = W[(size_t)(kb*64 + kl)*DD + noff + tn];
    }
    __syncthreads();
    #pragma unroll
    for (int r = 0; r < 16; ++r) {
        const int nl = tr*16 + r;
        wt[(size_t)(nbase + nl)*DD + kb*64 + tn] = (_Float16)T[tn][nl];
    }
}

// ---------------- qkv via MFMA ----------------
__global__ __launch_bounds__(64) void gemm_qkv(
    const float* __restrict__ hg, const int* __restrict__ mask,
    const _Float16* __restrict__ wt,
    _Float16* __restrict__ q16, _Float16* __restrict__ k16, _Float16* __restrict__ v16h)
{
    const int l  = threadIdx.x;
    const int lo = l & 15, g = l >> 4;
    const int bid = blockIdx.x;         // 128 row-tiles x 24 col-tiles
    const int rt = bid / 24, ct = bid % 24;
    const int R0 = rt*16, C0 = ct*32;
    const int row = R0 + lo;
    const float msc = (mask[row] != 0) ? 1.f : 0.f;

    const float*    xrow = hg + (size_t)row*DD;
    const _Float16* w0   = wt + (size_t)(C0 + lo)*DD;
    const _Float16* w1   = wt + (size_t)(C0 + 16 + lo)*DD;
    f32x4 ac0 = {0.f,0.f,0.f,0.f}, ac1 = {0.f,0.f,0.f,0.f};
    #pragma unroll
    for (int kk = 0; kk < 16; ++kk) {
        const float4 xv = *(const float4*)(xrow + kk*16 + g*4);
        f16x4 a;
        a[0] = (_Float16)(xv.x * msc);
        a[1] = (_Float16)(xv.y * msc);
        a[2] = (_Float16)(xv.z * msc);
        a[3] = (_Float16)(xv.w * msc);
        const f16x4 b0 = *(const f16x4*)(w0 + kk*16 + g*4);
        const f16x4 b1 = *(const f16x4*)(w1 + kk*16 + g*4);
        ac0 = __builtin_amdgcn_mfma_f32_16x16x16f16(a, b0, ac0, 0, 0, 0);
        ac1 = __builtin_amdgcn_mfma_f32_16x16x16f16(a, b1, ac1, 0, 0, 0);
    }
    const float qscale = 0.17677669529663687f; // 1/sqrt(32)
    #pragma unroll
    for (int ci = 0; ci < 2; ++ci) {
        const f32x4 ac = ci ? ac1 : ac0;
        const int col = C0 + ci*16 + lo;
        const int seg = col >> 8;          // 0=q 1=k 2=v
        const int cc  = col & 255;
        #pragma unroll
        for (int r = 0; r < 4; ++r) {
            const int ro = R0 + g*4 + r;
            const float val = ac[r];
            if (seg == 0)      q16[(size_t)ro*DD + cc] = (_Float16)val;
            else if (seg == 1) k16[(size_t)ro*DD + cc] = (_Float16)(val * qscale);
            else               v16h[((size_t)(ro >> 1)*DD + cc)*2 + (ro & 1)] = (_Float16)val;
        }
    }
}

// ---------------- kernel A: bias-MLP + QK, i-tile=16 (R13-exact, best-known) ----------------
// block = (b, i-tile of 16, j-eighth of 64). 1024 blocks, 4 waves; wave w owns
// j-tile je*64 + w*16. QK deferred to after the MLP loop -> 60 VGPR, no spill.
// launch_bounds(256,3) is the mapped spill-free optimum:
//   (256,3)=60VGPR/42us; (256,4)=no gain; (256,6)/(256,8)=spill meltdown.
__global__ __launch_bounds__(256, 3) void bias_qk(
    const _Float16* __restrict__ q16, const _Float16* __restrict__ k16,
    const float* __restrict__ p, const int* __restrict__ side, const int* __restrict__ mask,
    const float* __restrict__ W1, const float* __restrict__ b1,
    const float* __restrict__ W2, const float* __restrict__ b2,
    unsigned* __restrict__ logitsH)
{
    __shared__ float bsm[4][16*132];   // per-wave logits [i][h*16 + j], stride 132
    __shared__ float pis[16][2];
    __shared__ int   sis[16];

    const int t  = threadIdx.x;
    const int w  = t >> 6;
    const int l  = t & 63;
    const int lo = l & 15;
    const int g  = l >> 4;

    const int bid = blockIdx.x;
    const int b   = bid >> 8;
    const int it  = (bid >> 3) & 31;
    const int je  = bid & 7;
    const int i0  = it * 16;
    const int jb  = je * 64 + w * 16;   // this wave's j-tile
    const int j   = jb + lo;            // this lane's key column

    if (t < 16) {
        const float2 pp = ((const float2*)p)[b*NN + i0 + t];
        pis[t][0] = pp.x; pis[t][1] = pp.y;
        sis[t] = side[b*NN + i0 + t];
    }
    __syncthreads();

    const f16x4 z4 = {(_Float16)0.f,(_Float16)0.f,(_Float16)0.f,(_Float16)0.f};
    const f32x4 zf = {0.f,0.f,0.f,0.f};
    const h2 zz = {(_Float16)0.f, (_Float16)0.f};

    // A1: W1ext^T[hid][k]  (k: 0..3 feats, 4 bias-one, 5..15 zero)
    f16x4 a1[16];
    #pragma unroll
    for (int m = 0; m < 16; ++m) {
        const int hid = m*16 + lo;
        f16x4 v = z4;
        const float w0 = W1[hid], w1 = W1[256+hid], w2 = W1[512+hid], w3 = W1[768+hid];
        const float bb1 = b1[hid];
        if (g == 0) { v[0]=(_Float16)w0; v[1]=(_Float16)w1; v[2]=(_Float16)w2; v[3]=(_Float16)w3; }
        else if (g == 1) { v[0]=(_Float16)bb1; }
        a1[m] = v;
    }
    // A2: W2^T[h][hid], rows 8..15 zero
    f16x4 a2[16];
    #pragma unroll
    for (int s = 0; s < 16; ++s) {
        const int kb4 = s*16 + g*4;
        const int hs  = lo & 7;
        f16x4 v;
        v[0] = (_Float16)W2[(kb4+0)*HH + hs];
        v[1] = (_Float16)W2[(kb4+1)*HH + hs];
        v[2] = (_Float16)W2[(kb4+2)*HH + hs];
        v[3] = (_Float16)W2[(kb4+3)*HH + hs];
        a2[s] = (lo < 8) ? v : z4;
    }
    // b2 addend for epilogue rows h = g*4+r (only l<32 stores)
    float b2v[4];
    #pragma unroll
    for (int r = 0; r < 4; ++r) b2v[r] = (g < 2) ? b2[(g*4 + r) & 7] : 0.f;

    const float2 pj = ((const float2*)p)[b*NN + j];
    const int   sj  = side[b*NN + j];
    const float km  = mask[b*NN + j] ? 0.f : -3.0e4f;

    float* bw = &bsm[w][0];

    // ---- MLP: 16 pair-groups (group = query row i, cols = 16 j) ----
    #pragma unroll 2
    for (int i = 0; i < 16; ++i) {
        const float pix = pis[i][0], piy = pis[i][1];
        const int   sii = sis[i];
        const float dx = pix - pj.x;
        const float dy = piy - pj.y;
        const float di = fmaxf(sqrtf(dx*dx + dy*dy), 1e-6f);
        const float tm = (sii == sj) ? 1.f : 0.f;
        const h2 fA = pk2(dx, dy);   // RNE on features
        const h2 fB = pk2(di, tm);
        f16x4 bf = z4;
        if (g == 0) { bf[0]=fA[0]; bf[1]=fA[1]; bf[2]=fB[0]; bf[3]=fB[1]; }
        else if (g == 1) { bf[0] = (_Float16)1.f; }

        f32x4 e0 = zf, e1 = zf;
        #pragma unroll
        for (int s = 0; s < 16; ++s) {
            const f32x4 c1 = __builtin_amdgcn_mfma_f32_16x16x16f16(a1[s], bf, zf, 0, 0, 0);
            const h2 p01 = pkz(c1[0], c1[1]);   // RTZ on hidden
            const h2 p23 = pkz(c1[2], c1[3]);
            const h2 r01 = __builtin_elementwise_max(p01, zz);
            const h2 r23 = __builtin_elementwise_max(p23, zz);
            f16x4 hb;
            hb[0]=r01[0]; hb[1]=r01[1]; hb[2]=r23[0]; hb[3]=r23[1];
            if (s & 1) e1 = __builtin_amdgcn_mfma_f32_16x16x16f16(a2[s], hb, e1, 0, 0, 0);
            else       e0 = __builtin_amdgcn_mfma_f32_16x16x16f16(a2[s], hb, e0, 0, 0, 0);
        }
        if (l < 32) {
            #pragma unroll
            for (int r = 0; r < 4; ++r)
                bw[i*132 + (g*4 + r)*16 + lo] = e0[r] + e1[r] + b2v[r] + km;
        }
    }

    asm volatile("s_waitcnt lgkmcnt(0)" ::: "memory");
    __builtin_amdgcn_sched_barrier(0);

    // ---- QK (deferred): per head, 2 MFMA (K=32) then merge into LDS ----
    {
        const _Float16* qbase = q16 + (size_t)(b*NN + i0 + lo)*DD;
        const _Float16* kbase = k16 + (size_t)(b*NN + j)*DD;
        #pragma unroll
        for (int h = 0; h < 8; ++h) {
            const f16x4 q0  = *(const f16x4*)(qbase + h*32 + g*4);
            const f16x4 q1  = *(const f16x4*)(qbase + h*32 + 16 + g*4);
            const f16x4 kf0 = *(const f16x4*)(kbase + h*32 + g*4);
            const f16x4 kf1 = *(const f16x4*)(kbase + h*32 + 16 + g*4);
            f32x4 a  = __builtin_amdgcn_mfma_f32_16x16x16f16(q0, kf0, zf, 0, 0, 0);
            f32x4 qk = __builtin_amdgcn_mfma_f32_16x16x16f16(q1, kf1, a, 0, 0, 0);
            // C: row i = g*4+r, col j = lo
            #pragma unroll
            for (int r = 0; r < 4; ++r)
                bw[(g*4 + r)*132 + h*16 + lo] += qk[r];
        }
    }

    asm volatile("s_waitcnt lgkmcnt(0)" ::: "memory");
    __builtin_amdgcn_sched_barrier(0);

    // ---- pack f16 j-pairs and store: iter u = query row i; lane -> (h, jp) ----
    {
        const int hh = (l >> 3) & 7;
        const int jp = l & 7;
        #pragma unroll
        for (int u = 0; u < 16; ++u) {
            const float2 v2 = *(const float2*)&bw[u*132 + hh*16 + 2*jp];
            logitsH[((size_t)((b*NN + i0 + u)*HH + hh))*(NN/2) + (jb >> 1) + jp] =
                pk2u(v2.x, v2.y);
        }
    }
}

// ---------------- kernel B: softmax + PV (R13-exact) ----------------
__global__ __launch_bounds__(256, 4) void attn_sm(
    const unsigned* __restrict__ logitsH, const unsigned* __restrict__ v16p,
    float* __restrict__ ao)
{
    __shared__ unsigned Lgh[16][260];
    __shared__ float red[16][16];
    __shared__ float mx[16];
    __shared__ float rs[16];

    const int t  = threadIdx.x;
    const int b  = blockIdx.x / (NN/2);
    const int i0 = (blockIdx.x % (NN/2)) * 2;

    #pragma unroll
    for (int ii = 0; ii < 2; ++ii)
        #pragma unroll
        for (int hh = 0; hh < HH; ++hh)
            Lgh[ii*8 + hh][t] = logitsH[((size_t)((b*NN + i0 + ii)*HH + hh))*(NN/2) + t];
    __syncthreads();

    const int combo = t >> 4;
    const int sub   = t & 15;
    {
        h2 pm = u2h(0xFC00FC00u);
        for (int jp = sub; jp < NN/2; jp += 16)
            pm = __builtin_elementwise_max(pm, u2h(Lgh[combo][jp]));
        red[combo][sub] = fmaxf((float)pm[0], (float)pm[1]);
    }
    __syncthreads();
    if (t < 16) {
        float mm = red[t][0];
        #pragma unroll
        for (int s = 1; s < 16; ++s) mm = fmaxf(mm, red[t][s]);
        mx[t] = mm;
    }
    __syncthreads();
    {
        const float M = mx[combo];
        float s = 0.f;
        for (int jp = sub; jp < NN/2; jp += 16) {
            const h2 lg = u2h(Lgh[combo][jp]);
            const float e0 = __expf((float)lg[0] - M);
            const float e1 = __expf((float)lg[1] - M);
            s += e0 + e1;
            Lgh[combo][jp] = pk2u(e0, e1);
        }
        red[combo][sub] = s;
    }
    __syncthreads();
    if (t < 16) {
        float s = 0.f;
        #pragma unroll
        for (int ss = 0; ss < 16; ++ss) s += red[t][ss];
        rs[t] = 1.f / s;
    }
    __syncthreads();

    {
        const int c = t;
        const int hh = c >> 5;
        const unsigned* vb = v16p + (size_t)b*(NN/2)*DD + c;
        float o[2] = {0.f, 0.f};
        for (int jp = 0; jp < NN/2; ++jp) {
            const h2 vp = u2h(vb[(size_t)jp*DD]);
            #pragma unroll
            for (int ii = 0; ii < 2; ++ii)
                o[ii] = dot2(u2h(Lgh[ii*8 + hh][jp]), vp, o[ii]);
        }
        #pragma unroll
        for (int ii = 0; ii < 2; ++ii)
            ao[(size_t)(b*NN + i0 + ii)*DD + c] = o[ii] * rs[ii*8 + hh];
    }
}

// ---------------- output projection via MFMA (R13-exact) ----------------
__global__ __launch_bounds__(64) void gemm_o(
    const float* __restrict__ X, const _Float16* __restrict__ wt,
    float* __restrict__ Y)
{
    const int l  = threadIdx.x;
    const int lo = l & 15, g = l >> 4;
    const int bid = blockIdx.x;         // 128 row-tiles x 8 col-tiles
    const int rt = bid >> 3, ct = bid & 7;
    const int R0 = rt*16, C0 = ct*32;
    const int row = R0 + lo;

    const float*    xrow = X + (size_t)row*DD;
    const _Float16* w0   = wt + (size_t)(C0 + lo)*DD;
    const _Float16* w1   = wt + (size_t)(C0 + 16 + lo)*DD;
    f32x4 ac0 = {0.f,0.f,0.f,0.f}, ac1 = {0.f,0.f,0.f,0.f};
    #pragma unroll
    for (int kk = 0; kk < 16; ++kk) {
        const float4 xv = *(const float4*)(xrow + kk*16 + g*4);
        f16x4 a;
        a[0] = (_Float16)xv.x;
        a[1] = (_Float16)xv.y;
        a[2] = (_Float16)xv.z;
        a[3] = (_Float16)xv.w;
        const f16x4 b0 = *(const f16x4*)(w0 + kk*16 + g*4);
        const f16x4 b1 = *(const f16x4*)(w1 + kk*16 + g*4);
        ac0 = __builtin_amdgcn_mfma_f32_16x16x16f16(a, b0, ac0, 0, 0, 0);
        ac1 = __builtin_amdgcn_mfma_f32_16x16x16f16(a, b1, ac1, 0, 0, 0);
    }
    #pragma unroll
    for (int ci = 0; ci < 2; ++ci) {
        const f32x4 ac = ci ? ac1 : ac0;
        const int col = C0 + ci*16 + lo;
        #pragma unroll
        for (int r = 0; r < 4; ++r)
            Y[(size_t)(R0 + g*4 + r)*DD + col] = ac[r];
    }
}

extern "C" void kernel_launch(void* const* d_in, const int* in_sizes, int n_in,
                              void* d_out, int out_size, void* d_ws, size_t ws_size,
                              hipStream_t stream) {
    const float* hg   = (const float*)d_in[0];
    const float* p    = (const float*)d_in[1];
    const int*   side = (const int*)d_in[2];
    const int*   mask = (const int*)d_in[3];
    const float* Wq   = (const float*)d_in[4];
    const float* Wk   = (const float*)d_in[5];
    const float* Wv   = (const float*)d_in[6];
    const float* Wo   = (const float*)d_in[7];
    const float* W1   = (const float*)d_in[8];
    const float* b1   = (const float*)d_in[9];
    const float* W2   = (const float*)d_in[10];
    const float* b2   = (const float*)d_in[11];

    float* ws = (float*)d_ws;
    float* ao = ws;                                   // BND f32
    _Float16* q16 = (_Float16*)(ws + BND);            // BND f16
    _Float16* k16 = q16 + BND;                        // BND f16
    _Float16* v16 = k16 + BND;                        // BND f16 (packed pairs)
    unsigned* logitsH = (unsigned*)(v16 + BND);       // B*N*H*(N/2) dwords
    _Float16* wt16 = (_Float16*)(logitsH + (size_t)BB*NN*HH*(NN/2));  // [1024][256]

    pack_wt<<<64, 256, 0, stream>>>(Wq, Wk, Wv, Wo, wt16);
    gemm_qkv<<<128*24, 64, 0, stream>>>(hg, mask, wt16, q16, k16, v16);
    bias_qk<<<1024, 256, 0, stream>>>(q16, k16, p, side, mask, W1, b1, W2, b2, logitsH);
    attn_sm<<<BB*(NN/2), 256, 0, stream>>>(logitsH, (const unsigned*)v16, ao);
    gemm_o<<<128*8, 64, 0, stream>>>(ao, wt16 + (size_t)768*DD, (float*)d_out);
}